// Round 1
// 143.555 us; speedup vs baseline: 1.0118x; 1.0118x over previous
//
#include <hip/hip_runtime.h>
#include <hip/hip_bf16.h>
#include <math.h>

#define ICH   3
#define OCH   16
#define ID    18
#define IH    34
#define IW    34
#define OD    16
#define OH    32
#define OW    32
#define NB    128
#define SPATIAL  (OD * OH * OW)     // 16384 per (b,c)
#define EPSV     1e-5f

typedef __fp16 fp16x2 __attribute__((ext_vector_type(2)));

// Tiny pre-pass: transpose weights [oc][k=81] -> [k=81][oc=16] so the conv's
// per-(ic,kd,kh) weight group (48 floats) is CONTIGUOUS -> 3x s_load_dwordx16
// instead of 48 scattered 4B s_load_dword.
__global__ void transpose_w_kernel(const float* __restrict__ cw,
                                   float* __restrict__ wt) {
    const int i = blockIdx.x * 256 + threadIdx.x;
    if (i < OCH * 81) {
        const int c = i / 81, k = i - c * 81;
        wt[k * OCH + c] = cw[i];
    }
}

// ===== conv v8: UNCHANGED from the 145us baseline (R15 structure).
// Do NOT: raise min-waves (R2/R3 spill), LDS-stage x (R1-R8), MFMA im2col
// (R13), fp16 x staging (R5), grid caps/fusion (R11), tile shrink (R8).
__global__ __launch_bounds__(256, 2) void conv_stats_kernel(
    const float* __restrict__ x, const float* __restrict__ wt,
    const float* __restrict__ cb, const float* __restrict__ mult,
    unsigned short* __restrict__ y, float* __restrict__ stats)
{
    __shared__ float wsum[4][OCH], wsq[4][OCH];

    const int blk = blockIdx.x;
    const int b = blk >> 4;
    const int d = blk & 15;
    const int tid = threadIdx.x;

    const int h  = tid >> 3;        // 0..31
    const int wq = (tid & 7) << 2;  // 0,4,...,28

    float acc[OCH][4];
#pragma unroll
    for (int c = 0; c < OCH; c++) {
        const float bv = cb[c];
        acc[c][0] = bv; acc[c][1] = bv; acc[c][2] = bv; acc[c][3] = bv;
    }

    for (int ic = 0; ic < ICH; ic++) {
        for (int kd = 0; kd < 3; kd++) {
            const float* plane = x + ((size_t)(b * ICH + ic) * ID + (d + kd)) * (IH * IW);
            const float* wgrp  = wt + (ic * 3 + kd) * 3 * 48;   // 3 kh x 48 floats
#pragma unroll
            for (int kh = 0; kh < 3; kh++) {
                const float* row = plane + (size_t)(h + kh) * IW + wq;
                const float4 v0 = *(const float4*)row;
                const float2 v1 = *(const float2*)(row + 4);
                float in[6];
                in[0] = v0.x; in[1] = v0.y; in[2] = v0.z; in[3] = v0.w;
                in[4] = v1.x; in[5] = v1.y;
                const float* wrow = wgrp + kh * 48;             // contiguous 48
#pragma unroll
                for (int kw = 0; kw < 3; kw++) {
#pragma unroll
                    for (int c = 0; c < OCH; c++) {
                        const float wv = wrow[kw * OCH + c];    // s_load_dwordx16 path
                        acc[c][0] = fmaf(in[kw + 0], wv, acc[c][0]);
                        acc[c][1] = fmaf(in[kw + 1], wv, acc[c][1]);
                        acc[c][2] = fmaf(in[kw + 2], wv, acc[c][2]);
                        acc[c][3] = fmaf(in[kw + 3], wv, acc[c][3]);
                    }
                }
            }
        }
    }

    // ---- multiplier fold, stats, fp16 store (v_cvt_pkrtz) ----
    float ssum[OCH], ssq[OCH];
#pragma unroll
    for (int c = 0; c < OCH; c++) {
        const float m = mult[c];
        const float o0 = acc[c][0] * m, o1 = acc[c][1] * m;
        const float o2 = acc[c][2] * m, o3 = acc[c][3] * m;
        ssum[c] = (o0 + o1) + (o2 + o3);
        ssq[c]  = (o0 * o0 + o1 * o1) + (o2 * o2 + o3 * o3);
        const size_t yi = ((size_t)(b * OCH + c) * OD + d) * (OH * OW) + h * OW + wq;
        union { fp16x2 h; unsigned int u; } p01, p23;
        p01.h = __builtin_amdgcn_cvt_pkrtz(o0, o1);
        p23.h = __builtin_amdgcn_cvt_pkrtz(o2, o3);
        uint2 pk; pk.x = p01.u; pk.y = p23.u;
        *(uint2*)&y[yi] = pk;
    }

    // ---- block reduction of stats, per-block partial write (no atomics) ----
#pragma unroll
    for (int c = 0; c < OCH; c++) {
        for (int off = 32; off > 0; off >>= 1) {
            ssum[c] += __shfl_down(ssum[c], off);
            ssq[c]  += __shfl_down(ssq[c], off);
        }
    }
    const int wave = tid >> 6, lane = tid & 63;
    if (lane == 0) {
#pragma unroll
        for (int c = 0; c < OCH; c++) { wsum[wave][c] = ssum[c]; wsq[wave][c] = ssq[c]; }
    }
    __syncthreads();
    if (tid < OCH) {
        float s = 0.0f, q = 0.0f;
#pragma unroll
        for (int k = 0; k < 4; k++) { s += wsum[k][tid]; q += wsq[k][tid]; }
        const int sbase = ((b * OD + d) * OCH + tid) * 2;
        stats[sbase + 0] = s;
        stats[sbase + 1] = q;
    }
}

// ===== NEW: per-(b,c) norm params. Folds stats-sum, rsqrt, and BOTH
// multiplier applications into {A, B, L, H} so the hot kernel does
// out_c = med3(v*A + B, L, H) per element.  clamp(n,-1,1)*m == clamp(n*m,
// -|m|, +|m|) exactly (clamped branches produce +-m exactly; in-range branch
// same product). 2048 (b,c) pairs -> 8 blocks. Removes the per-block serial
// stats prologue + __syncthreads from the 2048-block hot kernel.
__global__ void params_kernel(const float* __restrict__ stats,
                              const float* __restrict__ mult,
                              float4* __restrict__ prm)
{
    const int i = blockIdx.x * 256 + threadIdx.x;   // (b,c) pair
    if (i < NB * OCH) {
        const int b = i >> 4, c = i & 15;
        float s = 0.0f, q = 0.0f;
        for (int dd = 0; dd < OD; dd++) {
            s += stats[((b * OD + dd) * OCH + c) * 2 + 0];
            q += stats[((b * OD + dd) * OCH + c) * 2 + 1];
        }
        const float mean = s * (1.0f / (float)SPATIAL);
        float var = q * (1.0f / (float)SPATIAL) - mean * mean;
        var = fmaxf(var, 0.0f);
        const float rs = rsqrtf(var + EPSV);
        const float m  = mult[c];
        float4 p;
        p.x = rs * m;             // A
        p.y = -mean * rs * m;     // B
        p.z = -fabsf(m);          // L
        p.w =  fabsf(m);          // H
        prm[i] = p;
    }
}

// ===== norm_max v2: 8 positions/thread via uint4 (16 B/lane = 1 KB/wave
// coalescing sweet spot, was 8 B uint2). All 16 channel loads issued
// up-front (16 KB in flight per wave). No LDS, no barrier, no prologue.
// 4 VALU/element: cvt, fma, med3-clamp, max. ~95 VGPR est -> 4+ waves/SIMD.
__global__ __launch_bounds__(256, 4) void norm_max_kernel(
    const unsigned short* __restrict__ y, const float4* __restrict__ prm,
    float* __restrict__ out)
{
    const int blk = blockIdx.x;     // NB*8 = 1024
    const int b   = blk >> 3;
    const int seg = blk & 7;
    const int tid = threadIdx.x;

    const int s = seg * 2048 + tid * 8;                  // 8 positions
    const unsigned short* yb = y + (size_t)b * OCH * SPATIAL + s;

    // issue all 16 streaming loads first -> max MLP
    uint4 v[OCH];
#pragma unroll
    for (int c = 0; c < OCH; c++) {
        v[c] = *(const uint4*)(yb + (size_t)c * SPATIAL);
    }

    const float4* pb = prm + b * OCH;

    float mx[8];
#pragma unroll
    for (int j = 0; j < 8; j++) mx[j] = -INFINITY;

#pragma unroll
    for (int c = 0; c < OCH; c++) {
        const float4 p = pb[c];          // wave-uniform addr -> L1 broadcast
        const float A = p.x, Bv = p.y, L = p.z, H = p.w;
        union { uint4 u4; unsigned int u[4]; } vv; vv.u4 = v[c];
#pragma unroll
        for (int w = 0; w < 4; w++) {
            union { unsigned int u; __fp16 h[2]; } a; a.u = vv.u[w];
            float f0 = fmaf((float)a.h[0], A, Bv);
            float f1 = fmaf((float)a.h[1], A, Bv);
            f0 = fminf(fmaxf(f0, L), H);                 // v_med3_f32 idiom
            f1 = fminf(fmaxf(f1, L), H);
            mx[2 * w]     = fmaxf(mx[2 * w],     f0);
            mx[2 * w + 1] = fmaxf(mx[2 * w + 1], f1);
        }
    }

    float* ob = out + (size_t)b * SPATIAL + s;
    float4 o0, o1;
    o0.x = mx[0]; o0.y = mx[1]; o0.z = mx[2]; o0.w = mx[3];
    o1.x = mx[4]; o1.y = mx[5]; o1.z = mx[6]; o1.w = mx[7];
    *(float4*)ob       = o0;
    *(float4*)(ob + 4) = o1;
}

extern "C" void kernel_launch(void* const* d_in, const int* in_sizes, int n_in,
                              void* d_out, int out_size, void* d_ws, size_t ws_size,
                              hipStream_t stream) {
    const float* x    = (const float*)d_in[0];
    const float* cw   = (const float*)d_in[1];
    const float* cb   = (const float*)d_in[2];
    const float* mult = (const float*)d_in[3];
    float* out = (float*)d_out;

    // ws: y fp16 (64 MB) | stats partials (256 KB) | prm (32 KB) | wt (5.2 KB)
    unsigned short* y = (unsigned short*)d_ws;
    float* stats = (float*)((char*)d_ws + (size_t)NB * OCH * SPATIAL * sizeof(unsigned short));
    float4* prm  = (float4*)(stats + NB * OD * OCH * 2);
    float* wt    = (float*)(prm + NB * OCH);

    transpose_w_kernel<<<6, 256, 0, stream>>>(cw, wt);
    conv_stats_kernel<<<NB * 16, 256, 0, stream>>>(x, wt, cb, mult, y, stats);
    params_kernel<<<8, 256, 0, stream>>>(stats, mult, prm);
    norm_max_kernel<<<NB * 8, 256, 0, stream>>>(y, prm, out);
}